// Round 9
// baseline (706.432 us; speedup 1.0000x reference)
//
#include <hip/hip_runtime.h>

#define T_STEPS 1024
#define BATCH 2048
#define BTILE 8
#define HS 36   // LDS row stride in u32 words; 36 % 32 == 4 -> conflict-free b128 reads

typedef short short8 __attribute__((ext_vector_type(8)));
typedef float f32x4 __attribute__((ext_vector_type(4)));
typedef float f32x2 __attribute__((ext_vector_type(2)));

__device__ __forceinline__ float fast_rcp(float x) {
#if __has_builtin(__builtin_amdgcn_rcpf)
    return __builtin_amdgcn_rcpf(x);
#else
    return 1.0f / x;
#endif
}

__device__ __forceinline__ float fast_exp2(float x) {
#if __has_builtin(__builtin_amdgcn_exp2f)
    return __builtin_amdgcn_exp2f(x);
#else
    return exp2f(x);
#endif
}

__device__ __forceinline__ float sigf(float x) {
    return fast_rcp(1.0f + fast_exp2(-1.44269504f * x));
}

__device__ __forceinline__ float tanh_fast(float x) {
    float e = fast_exp2(2.88539008f * x);
    return 1.0f - 2.0f * fast_rcp(e + 1.0f);
}

// packed (2-cell) sigmoid / tanh
__device__ __forceinline__ f32x2 sigf2(f32x2 v) {
    f32x2 t = v * (-1.44269504f);
    f32x2 e = {fast_exp2(t[0]), fast_exp2(t[1])};
    e = e + 1.0f;
    return f32x2{fast_rcp(e[0]), fast_rcp(e[1])};
}
__device__ __forceinline__ f32x2 tanh2(f32x2 v) {
    f32x2 t = v * 2.88539008f;
    f32x2 e = {fast_exp2(t[0]), fast_exp2(t[1])};
    e = e + 1.0f;
    f32x2 r = {fast_rcp(e[0]), fast_rcp(e[1])};
    return 1.0f - 2.0f * r;
}

// float -> bf16 bits (RNE) — setup only
__device__ __forceinline__ unsigned f2bf(float x) {
    unsigned u = __float_as_uint(x);
    unsigned r = u + 0x7FFFu + ((u >> 16) & 1u);
    return r >> 16;
}
__device__ __forceinline__ float bf2f(unsigned b) {
    return __uint_as_float(b << 16);
}

// packed bf16 convert: dst = {hi16=bf16(b), lo16=bf16(a)}, RNE
__device__ __forceinline__ unsigned cvt_pk_bf16(float a, float b) {
    unsigned r;
    asm("v_cvt_pk_bf16_f32 %0, %1, %2" : "=v"(r) : "v"(a), "v"(b));
    return r;
}

// 8 batches (MFMA cols 0..7), 8 waves. Wave w = v + 4s (v=w&3, s=w>>2)
// computes unit-group v (tiles {v,v+4,v+8,v+12}: all 4 gates of units
// 16v..16v+15) — duplicated with its pair wave — and activates the cells in
// accumulator regs {2s, 2s+1}: lane 16q+n owns cells (batch n, units
// 16v+4q+2s, +2s+1) with ALL 4 gates in-lane. No gate redistribution, no
// partner DPP for packing (adjacent units pack directly via cvt_pk).
// 256 blocks = 1/CU, 2 waves/SIMD; one barrier per step.
__global__ __launch_bounds__(512, 2)
void lstm_v9_kernel(const float* __restrict__ input,
                    const float* __restrict__ W_ih0,
                    const float* __restrict__ W_hh0,
                    const float* __restrict__ b_ih0,
                    const float* __restrict__ b_hh0,
                    const float* __restrict__ W_ih1,
                    const float* __restrict__ W_hh1,
                    const float* __restrict__ b_ih1,
                    const float* __restrict__ b_hh1,
                    float* __restrict__ out)
{
    const int tid = threadIdx.x;
    const int w   = tid >> 6;        // wave 0..7
    const int l   = tid & 63;
    const int q16 = l >> 4;
    const int n16 = l & 15;
    const int v   = w & 3;           // unit group
    const int s   = w >> 2;          // reg-pair selector
    const int uA  = 16 * v + 4 * q16 + 2 * s;   // even unit; uB = uA+1
    const int bbase = blockIdx.x * BTILE;

    __shared__ __align__(16) unsigned Hbuf[2][3][16][HS];   // 13.8 KB
    __shared__ float Xb[2][BTILE][65];                      // 4.2 KB
    __shared__ float Lst[16];                               // h1[0..7], c1[8..15]

    for (int i = tid; i < 2 * 3 * 16 * HS; i += 512)
        reinterpret_cast<unsigned*>(Hbuf)[i] = 0u;
    if (tid < 16) Lst[tid] = 0.0f;

    // ---- L1 A-fragments: tiles {v+4g}, g=0..3 ----
    short8 a1[4][2];
    #pragma unroll
    for (int g = 0; g < 4; ++g) {
        #pragma unroll
        for (int kt = 0; kt < 2; ++kt) {
            const float* p = W_hh0 + (size_t)(16 * (v + 4 * g) + n16) * 64 + kt * 32 + q16 * 8;
            short8 a;
            #pragma unroll
            for (int j = 0; j < 8; ++j) a[j] = (short)f2bf(p[j]);
            a1[g][kt] = a;
        }
    }
    // ---- L2 A-fragments (hi/lo split), rows m>=4 zero ----
    short8 a2h[2], a2l[2];
    #pragma unroll
    for (int kt = 0; kt < 2; ++kt) {
        short8 ah = {0,0,0,0,0,0,0,0}, al = {0,0,0,0,0,0,0,0};
        if (n16 < 4) {
            const float* p = W_ih1 + (size_t)n16 * 64 + kt * 32 + q16 * 8;
            #pragma unroll
            for (int j = 0; j < 8; ++j) {
                unsigned hb = f2bf(p[j]);
                ah[j] = (short)hb;
                al[j] = (short)f2bf(p[j] - bf2f(hb));
            }
        }
        a2h[kt] = ah; a2l[kt] = al;
    }

    // activation constants: per-gate (cellA, cellB) packed pairs
    f32x2 wgp[4], bgp[4];
    #pragma unroll
    for (int g = 0; g < 4; ++g) {
        int rA = g * 64 + uA, rB = rA + 1;
        wgp[g] = f32x2{W_ih0[rA], W_ih0[rB]};
        bgp[g] = f32x2{b_ih0[rA] + b_hh0[rA], b_ih0[rB] + b_hh0[rB]};
    }
    float whh1v[4], b1v[4];
    #pragma unroll
    for (int g = 0; g < 4; ++g) { whh1v[g] = W_hh1[g]; b1v[g] = b_ih1[g] + b_hh1[g]; }

    const float* inrow = input + (size_t)(bbase + w) * T_STEPS;  // wave w owns batch w
    Xb[0][w][l] = inrow[l];
    float xnext = 0.0f;
    f32x2 c0 = {0.0f, 0.0f};

    __syncthreads();

    int par = 0;
    #pragma unroll 2
    for (int t = 0; t < T_STEPS; ++t) {
        if ((t & 63) == 0 && t + 64 < T_STEPS) xnext = inrow[t + 64 + l];
        const int cp = (t >> 6) & 1;

        // ---- B-fragments: h(t-1), batches in cols 0..7 ----
        const unsigned* Hrow = &Hbuf[par][0][n16][0];
        short8 hb0 = *reinterpret_cast<const short8*>(Hrow + 4 * q16);
        short8 hb1 = *reinterpret_cast<const short8*>(Hrow + 16 + 4 * q16);

        // ---- L1 MFMA: all 4 gates of units 16v..16v+15, 8 batches ----
        f32x4 accv[4];
        #pragma unroll
        for (int g = 0; g < 4; ++g) {
            f32x4 z = {0.0f, 0.0f, 0.0f, 0.0f};
            z = __builtin_amdgcn_mfma_f32_16x16x32_bf16(a1[g][0], hb0, z, 0, 0, 0);
            z = __builtin_amdgcn_mfma_f32_16x16x32_bf16(a1[g][1], hb1, z, 0, 0, 0);
            accv[g] = z;
        }

        // ---- layer-2 for step t-1 (round-robin over 8 waves) ----
        if (t > 0 && w == ((t - 1) & 7)) {
            const unsigned* Ch = &Hbuf[par][1][n16][0];
            const unsigned* Cl = &Hbuf[par][2][n16][0];
            short8 ch0 = *reinterpret_cast<const short8*>(Ch + 4 * q16);
            short8 ch1 = *reinterpret_cast<const short8*>(Ch + 16 + 4 * q16);
            short8 cl0 = *reinterpret_cast<const short8*>(Cl + 4 * q16);
            short8 cl1 = *reinterpret_cast<const short8*>(Cl + 16 + 4 * q16);
            float h1p = Lst[l & 7], c1p = Lst[8 + (l & 7)];
            f32x4 zA = {0.0f, 0.0f, 0.0f, 0.0f};
            f32x4 zB = {0.0f, 0.0f, 0.0f, 0.0f};
            zA = __builtin_amdgcn_mfma_f32_16x16x32_bf16(a2h[0], ch0, zA, 0, 0, 0);
            zB = __builtin_amdgcn_mfma_f32_16x16x32_bf16(a2l[1], ch1, zB, 0, 0, 0);
            zA = __builtin_amdgcn_mfma_f32_16x16x32_bf16(a2h[1], ch1, zA, 0, 0, 0);
            zB = __builtin_amdgcn_mfma_f32_16x16x32_bf16(a2h[0], cl0, zB, 0, 0, 0);
            zA = __builtin_amdgcn_mfma_f32_16x16x32_bf16(a2l[0], ch0, zA, 0, 0, 0);
            zB = __builtin_amdgcn_mfma_f32_16x16x32_bf16(a2h[1], cl1, zB, 0, 0, 0);
            f32x4 z = zA + zB;                 // valid at q16==0 lanes (rows=gates)
            float g1i = z[0] + b1v[0] + h1p * whh1v[0];
            float g1f = z[1] + b1v[1] + h1p * whh1v[1];
            float g1g = z[2] + b1v[2] + h1p * whh1v[2];
            float g1o = z[3] + b1v[3] + h1p * whh1v[3];
            float c1n = sigf(g1f) * c1p + sigf(g1i) * tanh_fast(g1g);
            float h1n = sigf(g1o) * tanh_fast(c1n);
            if (l < 8) {
                out[(size_t)(bbase + l) * T_STEPS + (t - 1)] = c1n;
                Lst[l] = h1n;
                Lst[8 + l] = c1n;
            }
        }

        // ---- activation: cells (n16, uA) and (n16, uB), fully in-lane ----
        f32x2 gin[4];
        if (s == 0) {                          // wave-uniform branch
            #pragma unroll
            for (int g = 0; g < 4; ++g) gin[g] = f32x2{accv[g][0], accv[g][1]};
        } else {
            #pragma unroll
            for (int g = 0; g < 4; ++g) gin[g] = f32x2{accv[g][2], accv[g][3]};
        }
        float x = Xb[cp][n16 & 7][t & 63];
        f32x2 xx = {x, x};
        f32x2 gp0 = gin[0] + (xx * wgp[0] + bgp[0]);   // i
        f32x2 gp1 = gin[1] + (xx * wgp[1] + bgp[1]);   // f
        f32x2 gp2 = gin[2] + (xx * wgp[2] + bgp[2]);   // g
        f32x2 gp3 = gin[3] + (xx * wgp[3] + bgp[3]);   // o

        f32x2 si = sigf2(gp0);
        f32x2 sf = sigf2(gp1);
        f32x2 tg = tanh2(gp2);
        f32x2 so = sigf2(gp3);
        f32x2 c0n = sf * c0 + si * tg;
        c0 = c0n;
        f32x2 h0n = so * tanh2(c0n);

        // ---- pack: adjacent units (uA,uB) -> one word each, no DPP ----
        unsigned hword  = cvt_pk_bf16(h0n[0], h0n[1]);
        unsigned chword = cvt_pk_bf16(c0n[0], c0n[1]);
        float loA = c0n[0] - __uint_as_float(chword << 16);
        float loB = c0n[1] - __uint_as_float(chword & 0xFFFF0000u);
        unsigned clword = cvt_pk_bf16(loA, loB);

        if (n16 < 8) {                          // batch rows 0..7 only
            int widx = 8 * v + 2 * q16 + s;     // = uA/2
            Hbuf[par ^ 1][0][n16][widx] = hword;
            Hbuf[par ^ 1][1][n16][widx] = chword;
            Hbuf[par ^ 1][2][n16][widx] = clword;
        }
        if ((t & 63) == 63 && t + 1 < T_STEPS) Xb[cp ^ 1][w][l] = xnext;

        __syncthreads();
        par ^= 1;
    }

    // ---- epilogue: layer-2 for step 1023 (wave 1023&7 == 7) ----
    if (w == 7) {
        const unsigned* Ch = &Hbuf[par][1][n16][0];
        const unsigned* Cl = &Hbuf[par][2][n16][0];
        short8 ch0 = *reinterpret_cast<const short8*>(Ch + 4 * q16);
        short8 ch1 = *reinterpret_cast<const short8*>(Ch + 16 + 4 * q16);
        short8 cl0 = *reinterpret_cast<const short8*>(Cl + 4 * q16);
        short8 cl1 = *reinterpret_cast<const short8*>(Cl + 16 + 4 * q16);
        float h1p = Lst[l & 7], c1p = Lst[8 + (l & 7)];
        f32x4 zA = {0.0f, 0.0f, 0.0f, 0.0f};
        f32x4 zB = {0.0f, 0.0f, 0.0f, 0.0f};
        zA = __builtin_amdgcn_mfma_f32_16x16x32_bf16(a2h[0], ch0, zA, 0, 0, 0);
        zB = __builtin_amdgcn_mfma_f32_16x16x32_bf16(a2l[1], ch1, zB, 0, 0, 0);
        zA = __builtin_amdgcn_mfma_f32_16x16x32_bf16(a2h[1], ch1, zA, 0, 0, 0);
        zB = __builtin_amdgcn_mfma_f32_16x16x32_bf16(a2h[0], cl0, zB, 0, 0, 0);
        zA = __builtin_amdgcn_mfma_f32_16x16x32_bf16(a2l[0], ch0, zA, 0, 0, 0);
        zB = __builtin_amdgcn_mfma_f32_16x16x32_bf16(a2h[1], cl1, zB, 0, 0, 0);
        f32x4 z = zA + zB;
        float g1i = z[0] + b1v[0] + h1p * whh1v[0];
        float g1f = z[1] + b1v[1] + h1p * whh1v[1];
        float g1g = z[2] + b1v[2] + h1p * whh1v[2];
        float g1o = z[3] + b1v[3] + h1p * whh1v[3];
        float c1n = sigf(g1f) * c1p + sigf(g1i) * tanh_fast(g1g);
        if (l < 8)
            out[(size_t)(bbase + l) * T_STEPS + (T_STEPS - 1)] = c1n;
    }
}

extern "C" void kernel_launch(void* const* d_in, const int* in_sizes, int n_in,
                              void* d_out, int out_size, void* d_ws, size_t ws_size,
                              hipStream_t stream) {
    const float* input = (const float*)d_in[0];
    const float* W_ih0 = (const float*)d_in[1];
    const float* W_hh0 = (const float*)d_in[2];
    const float* b_ih0 = (const float*)d_in[3];
    const float* b_hh0 = (const float*)d_in[4];
    const float* W_ih1 = (const float*)d_in[5];
    const float* W_hh1 = (const float*)d_in[6];
    const float* b_ih1 = (const float*)d_in[7];
    const float* b_hh1 = (const float*)d_in[8];
    float* out = (float*)d_out;

    dim3 grid(BATCH / BTILE);   // 256 blocks -> 1 block/CU, 2 waves/SIMD
    dim3 block(512);
    lstm_v9_kernel<<<grid, block, 0, stream>>>(
        input, W_ih0, W_hh0, b_ih0, b_hh0, W_ih1, W_hh1, b_ih1, b_hh1, out);
}